// Round 1
// baseline (3181.026 us; speedup 1.0000x reference)
//
#include <hip/hip_runtime.h>
#include <math.h>

// Problem: B=8, N=4096, D=1024, E=512, C=4096.
// M = B*N = 32768 rows.
// Pipeline:
//   cn   = normalize(codebook)           [4096, 512]
//   proj = x @ rp                        [32768, 512]   (NOT normalized: argmax-invariant)
//   per (m-tile, c-tile): partial argmax of proj @ cn^T -> pval/pidx [32768, 32]
//   final: reduce 32 partials -> out int32 [32768]
//
// ws layout (bytes):
//   cn    @ 0        : 4096*512*4  =  8 MB
//   proj  @ 8  MB    : 32768*512*4 = 64 MB
//   pval  @ 72 MB    : 32768*32*4  =  4 MB
//   pidx  @ 76 MB    : 32768*32*4  =  4 MB
// total 80 MB.

#define MT 128
#define NT 128
#define KT 16

__global__ __launch_bounds__(256) void k_norm_cb(const float* __restrict__ cb,
                                                 float* __restrict__ cn) {
    const int c = blockIdx.x;            // 4096 rows
    const int t = threadIdx.x;           // 256 threads
    const float* row = cb + (size_t)c * 512;
    float v0 = row[t];
    float v1 = row[t + 256];
    float ss = v0 * v0 + v1 * v1;
    // wave-64 butterfly then cross-wave via LDS
    #pragma unroll
    for (int o = 32; o > 0; o >>= 1) ss += __shfl_down(ss, o, 64);
    __shared__ float wsum[4];
    if ((t & 63) == 0) wsum[t >> 6] = ss;
    __syncthreads();
    float tot = wsum[0] + wsum[1] + wsum[2] + wsum[3];
    float s = 1.0f / fmaxf(sqrtf(tot), 1e-12f);
    float* orow = cn + (size_t)c * 512;
    orow[t] = v0 * s;
    orow[t + 256] = v1 * s;
}

// proj[32768,512] = x[32768,1024] @ rp[1024,512]
__global__ __launch_bounds__(256) void k_gemm1(const float* __restrict__ A,
                                               const float* __restrict__ Bm,
                                               float* __restrict__ Cm) {
    __shared__ float As[KT][MT];   // k-major
    __shared__ float Bs[KT][NT];
    const int t = threadIdx.x;
    const int nb = blockIdx.x;     // 0..3
    const int mb = blockIdx.y;     // 0..255
    const int tx = t & 15, ty = t >> 4;
    float acc[8][8] = {};
    const float* Ab = A + (size_t)(mb * MT) * 1024;
    const float* Bb = Bm + nb * NT;

    for (int k0 = 0; k0 < 1024; k0 += KT) {
        #pragma unroll
        for (int i = 0; i < 2; ++i) {
            int idx = i * 256 + t;           // 0..511
            // A tile: 128 rows x 16 k  (float4 along K, scatter k-major)
            int row = idx >> 2, kq = idx & 3;
            float4 v = *(const float4*)(Ab + (size_t)row * 1024 + k0 + kq * 4);
            As[kq * 4 + 0][row] = v.x;
            As[kq * 4 + 1][row] = v.y;
            As[kq * 4 + 2][row] = v.z;
            As[kq * 4 + 3][row] = v.w;
            // B tile: 16 k-rows x 128 cols (already k-major, contiguous)
            int kr = idx >> 5, c4 = idx & 31;
            float4 w = *(const float4*)(Bb + (size_t)(k0 + kr) * 512 + c4 * 4);
            *(float4*)&Bs[kr][c4 * 4] = w;
        }
        __syncthreads();
        #pragma unroll
        for (int k = 0; k < KT; ++k) {
            float4 a0 = *(const float4*)&As[k][ty * 4];
            float4 a1 = *(const float4*)&As[k][64 + ty * 4];
            float4 b0 = *(const float4*)&Bs[k][tx * 4];
            float4 b1 = *(const float4*)&Bs[k][64 + tx * 4];
            float a[8] = {a0.x, a0.y, a0.z, a0.w, a1.x, a1.y, a1.z, a1.w};
            float b[8] = {b0.x, b0.y, b0.z, b0.w, b1.x, b1.y, b1.z, b1.w};
            #pragma unroll
            for (int i = 0; i < 8; ++i)
                #pragma unroll
                for (int j = 0; j < 8; ++j)
                    acc[i][j] = fmaf(a[i], b[j], acc[i][j]);
        }
        __syncthreads();
    }
    #pragma unroll
    for (int i = 0; i < 8; ++i) {
        int row = (i < 4) ? (ty * 4 + i) : (64 + ty * 4 + (i - 4));
        size_t base = (size_t)(mb * MT + row) * 512 + nb * NT;
        *(float4*)(Cm + base + tx * 4)      = make_float4(acc[i][0], acc[i][1], acc[i][2], acc[i][3]);
        *(float4*)(Cm + base + 64 + tx * 4) = make_float4(acc[i][4], acc[i][5], acc[i][6], acc[i][7]);
    }
}

// per-(m-tile, c-tile) partial argmax of proj @ cn^T
__global__ __launch_bounds__(256) void k_sim(const float* __restrict__ P,
                                             const float* __restrict__ CN,
                                             float* __restrict__ pval,
                                             int* __restrict__ pidx) {
    __shared__ float As[KT][MT];
    __shared__ float Bs[KT][NT];
    __shared__ float rv[MT * 16];
    __shared__ int   ri[MT * 16];
    const int t = threadIdx.x;
    const int cbk = blockIdx.x;    // 0..31 c-tiles
    const int mb = blockIdx.y;     // 0..255 m-tiles
    const int tx = t & 15, ty = t >> 4;
    float acc[8][8] = {};
    const float* Ab = P + (size_t)(mb * MT) * 512;
    const float* Bb = CN + (size_t)(cbk * NT) * 512;

    for (int k0 = 0; k0 < 512; k0 += KT) {
        #pragma unroll
        for (int i = 0; i < 2; ++i) {
            int idx = i * 256 + t;           // 0..511
            int row = idx >> 2, kq = idx & 3;
            float4 v = *(const float4*)(Ab + (size_t)row * 512 + k0 + kq * 4);
            As[kq * 4 + 0][row] = v.x;
            As[kq * 4 + 1][row] = v.y;
            As[kq * 4 + 2][row] = v.z;
            As[kq * 4 + 3][row] = v.w;
            float4 w = *(const float4*)(Bb + (size_t)row * 512 + k0 + kq * 4);
            Bs[kq * 4 + 0][row] = w.x;
            Bs[kq * 4 + 1][row] = w.y;
            Bs[kq * 4 + 2][row] = w.z;
            Bs[kq * 4 + 3][row] = w.w;
        }
        __syncthreads();
        #pragma unroll
        for (int k = 0; k < KT; ++k) {
            float4 a0 = *(const float4*)&As[k][ty * 4];
            float4 a1 = *(const float4*)&As[k][64 + ty * 4];
            float4 b0 = *(const float4*)&Bs[k][tx * 4];
            float4 b1 = *(const float4*)&Bs[k][64 + tx * 4];
            float a[8] = {a0.x, a0.y, a0.z, a0.w, a1.x, a1.y, a1.z, a1.w};
            float b[8] = {b0.x, b0.y, b0.z, b0.w, b1.x, b1.y, b1.z, b1.w};
            #pragma unroll
            for (int i = 0; i < 8; ++i)
                #pragma unroll
                for (int j = 0; j < 8; ++j)
                    acc[i][j] = fmaf(a[i], b[j], acc[i][j]);
        }
        __syncthreads();
    }

    // per-thread best over its 8 c-slots, per m-row; c iterated ascending so
    // strict > keeps the first (numpy argmax tie semantics)
    #pragma unroll
    for (int i = 0; i < 8; ++i) {
        int row = (i < 4) ? (ty * 4 + i) : (64 + ty * 4 + (i - 4));
        float bv = -INFINITY;
        int bi = 0;
        #pragma unroll
        for (int j = 0; j < 8; ++j) {
            int cl = (j < 4) ? (tx * 4 + j) : (64 + tx * 4 + (j - 4));
            float v = acc[i][j];
            if (v > bv) { bv = v; bi = cl; }
        }
        rv[row * 16 + tx] = bv;
        ri[row * 16 + tx] = bi;
    }
    __syncthreads();
    if (t < MT) {
        float bv = -INFINITY;
        int bi = 0x7fffffff;
        #pragma unroll
        for (int j = 0; j < 16; ++j) {
            float v = rv[t * 16 + j];
            int ci = ri[t * 16 + j];
            if (v > bv || (v == bv && ci < bi)) { bv = v; bi = ci; }
        }
        int m = mb * MT + t;
        pval[(size_t)m * 32 + cbk] = bv;
        pidx[(size_t)m * 32 + cbk] = cbk * NT + bi;
    }
}

__global__ __launch_bounds__(256) void k_final(const float* __restrict__ pval,
                                               const int* __restrict__ pidx,
                                               int* __restrict__ out) {
    int r = blockIdx.x * 256 + threadIdx.x;
    if (r >= 32768) return;
    float bv = -INFINITY;
    int bi = 0x7fffffff;
    #pragma unroll
    for (int j = 0; j < 32; ++j) {
        float v = pval[(size_t)r * 32 + j];
        int ci = pidx[(size_t)r * 32 + j];
        if (v > bv || (v == bv && ci < bi)) { bv = v; bi = ci; }
    }
    out[r] = bi;
}

extern "C" void kernel_launch(void* const* d_in, const int* in_sizes, int n_in,
                              void* d_out, int out_size, void* d_ws, size_t ws_size,
                              hipStream_t stream) {
    const float* x  = (const float*)d_in[0];   // [8,4096,1024]
    const float* rp = (const float*)d_in[1];   // [1024,512]
    const float* cb = (const float*)d_in[2];   // [4096,512]
    int* out = (int*)d_out;                    // [32768] int32

    char* ws = (char*)d_ws;
    float* cn   = (float*)(ws);
    float* proj = (float*)(ws + ((size_t)8 << 20));
    float* pval = (float*)(ws + ((size_t)72 << 20));
    int*   pidx = (int*)  (ws + ((size_t)76 << 20));

    k_norm_cb<<<4096, 256, 0, stream>>>(cb, cn);
    k_gemm1<<<dim3(4, 256), 256, 0, stream>>>(x, rp, proj);
    k_sim<<<dim3(32, 256), 256, 0, stream>>>(proj, cn, pval, pidx);
    k_final<<<128, 256, 0, stream>>>(pval, pidx, out);
}

// Round 3
// 786.196 us; speedup vs baseline: 4.0461x; 4.0461x over previous
//
#include <hip/hip_runtime.h>
#include <math.h>

// B=8, N=4096, D=1024, E=512, C=4096.  M = 32768.
// Split-fp16 MFMA emulation of fp32 GEMM:
//   a = hi + lo/2048  (hi = f16(a), lo = f16((a-hi)*2048); residual ~2^-22 rel)
//   a.b ~= hi_a.hi_b + (hi_a.lo_b + lo_a.hi_b)/2048   -> 3 MFMAs, 2 accumulators
// Pipeline:
//   rpT_hi/lo [512][1024]  = split(transpose(rp))           (k_prep_rpt)
//   cn_hi/lo  [4096][512]  = split(normalize(codebook))     (k_norm_cb)
//   proj_hi/lo[32768][512] = split(x @ rp)                  (k_gemm1, MFMA)
//   partial argmax of proj @ cn^T per (m-tile, c-tile)      (k_sim, MFMA)
//   final reduce over 32 c-tiles                            (k_final)
//
// ws layout (MB): cn_h 0..4, cn_l 4..8, rpT_h 8..9, rpT_l 9..10,
//                 proj_h 10..42, proj_l 42..74, pval 74..78, pidx 78..82

typedef _Float16 half8 __attribute__((ext_vector_type(8)));
typedef _Float16 half4 __attribute__((ext_vector_type(4)));
typedef float f32x4 __attribute__((ext_vector_type(4)));

#define INV2048 (4.8828125e-4f)

struct Split { _Float16 h, l; };

__device__ __forceinline__ Split split_f32(float v) {
    Split s;
    s.h = (_Float16)v;
    s.l = (_Float16)((v - (float)s.h) * 2048.0f);
    return s;
}

__device__ __forceinline__ void gl_lds16(const void* g, void* l) {
    __builtin_amdgcn_global_load_lds(
        (const __attribute__((address_space(1))) unsigned int*)g,
        (__attribute__((address_space(3))) unsigned int*)l, 16, 0, 0);
}

// rp [1024,512] fp32 -> rpT_hi/lo [512,1024] f16 (transpose + split)
__global__ __launch_bounds__(256) void k_prep_rpt(const float* __restrict__ rp,
                                                  _Float16* __restrict__ th,
                                                  _Float16* __restrict__ tl) {
    __shared__ float tile[64][65];
    const int k0 = blockIdx.x * 64, n0 = blockIdx.y * 64;
    const int t = threadIdx.x;
    const int rr = t >> 6, cc = t & 63;
    #pragma unroll
    for (int i = 0; i < 16; ++i) {
        int r = i * 4 + rr;
        tile[r][cc] = rp[(size_t)(k0 + r) * 512 + n0 + cc];
    }
    __syncthreads();
    #pragma unroll
    for (int i = 0; i < 16; ++i) {
        int n = i * 4 + rr;
        Split s = split_f32(tile[cc][n]);
        size_t o = (size_t)(n0 + n) * 1024 + k0 + cc;
        th[o] = s.h;
        tl[o] = s.l;
    }
}

// codebook [4096,512] fp32 -> cn_hi/lo [4096,512] f16 (normalize + split)
__global__ __launch_bounds__(256) void k_norm_cb(const float* __restrict__ cb,
                                                 _Float16* __restrict__ ch,
                                                 _Float16* __restrict__ cl) {
    const int c = blockIdx.x;
    const int t = threadIdx.x;
    const float* row = cb + (size_t)c * 512;
    float v0 = row[t];
    float v1 = row[t + 256];
    float ss = v0 * v0 + v1 * v1;
    #pragma unroll
    for (int o = 32; o > 0; o >>= 1) ss += __shfl_down(ss, o, 64);
    __shared__ float wsum[4];
    if ((t & 63) == 0) wsum[t >> 6] = ss;
    __syncthreads();
    float s = 1.0f / fmaxf(sqrtf(wsum[0] + wsum[1] + wsum[2] + wsum[3]), 1e-12f);
    Split s0 = split_f32(v0 * s);
    ch[(size_t)c * 512 + t] = s0.h;
    cl[(size_t)c * 512 + t] = s0.l;
    Split s1 = split_f32(v1 * s);
    ch[(size_t)c * 512 + t + 256] = s1.h;
    cl[(size_t)c * 512 + t + 256] = s1.l;
}

// proj = x @ rp : M=32768, N=512, K=1024.  A converted fp32->split-f16 in staging,
// B = rpT (pre-split, [n][k] layout) via global_load_lds.
__global__ __launch_bounds__(256, 2) void k_gemm1(const float* __restrict__ X,
                                                  const _Float16* __restrict__ Bh,
                                                  const _Float16* __restrict__ Bl,
                                                  _Float16* __restrict__ Ph,
                                                  _Float16* __restrict__ Pl) {
    __shared__ _Float16 sAh[128 * 32], sAl[128 * 32], sBh[128 * 32], sBl[128 * 32];
    const int t = threadIdx.x;
    const int nb = blockIdx.x;   // 0..3
    const int mb = blockIdx.y;   // 0..255
    const int lane = t & 63, w = t >> 6;
    const int quad = lane >> 4, l15 = lane & 15;
    const int wm = w >> 1, wn = w & 1;

    f32x4 acc[4][4], acc2[4][4];
    const f32x4 z = {0.f, 0.f, 0.f, 0.f};
    #pragma unroll
    for (int i = 0; i < 4; ++i)
        #pragma unroll
        for (int j = 0; j < 4; ++j) { acc[i][j] = z; acc2[i][j] = z; }

    // B staging: wave w covers tile rows [w*32, w*32+32), 2 chunks of 16 rows
    const int srow = w * 32 + (lane >> 2);
    const int kcol = (lane & 3) * 8;
    const _Float16* gBh = Bh + (size_t)(nb * 128 + srow) * 1024 + kcol;
    const _Float16* gBl = Bl + (size_t)(nb * 128 + srow) * 1024 + kcol;
    const float* Xb = X + (size_t)(mb * 128) * 1024;

    for (int ks = 0; ks < 32; ++ks) {
        const int ko = ks * 32;
        __syncthreads();
        gl_lds16(gBh + ko, &sBh[w * 1024]);
        gl_lds16(gBh + ko + (size_t)16 * 1024, &sBh[w * 1024 + 512]);
        gl_lds16(gBl + ko, &sBl[w * 1024]);
        gl_lds16(gBl + ko + (size_t)16 * 1024, &sBl[w * 1024 + 512]);
        // A tile 128x32 fp32, convert to split f16
        #pragma unroll
        for (int i = 0; i < 4; ++i) {
            int c = i * 256 + t;           // 0..1023 chunks of 4
            int row = c >> 3, kq = (c & 7) * 4;
            float4 v = *(const float4*)(Xb + (size_t)row * 1024 + ko + kq);
            Split sx = split_f32(v.x), sy = split_f32(v.y);
            Split sz = split_f32(v.z), sw = split_f32(v.w);
            half4 hv, lv;
            hv.x = sx.h; hv.y = sy.h; hv.z = sz.h; hv.w = sw.h;
            lv.x = sx.l; lv.y = sy.l; lv.z = sz.l; lv.w = sw.l;
            *(half4*)&sAh[row * 32 + kq] = hv;
            *(half4*)&sAl[row * 32 + kq] = lv;
        }
        __syncthreads();
        half8 ah[4], al[4], bh[4], bl[4];
        #pragma unroll
        for (int i = 0; i < 4; ++i) {
            ah[i] = *(const half8*)&sAh[(wm * 64 + i * 16 + l15) * 32 + quad * 8];
            al[i] = *(const half8*)&sAl[(wm * 64 + i * 16 + l15) * 32 + quad * 8];
            bh[i] = *(const half8*)&sBh[(wn * 64 + i * 16 + l15) * 32 + quad * 8];
            bl[i] = *(const half8*)&sBl[(wn * 64 + i * 16 + l15) * 32 + quad * 8];
        }
        #pragma unroll
        for (int mi = 0; mi < 4; ++mi)
            #pragma unroll
            for (int ni = 0; ni < 4; ++ni) {
                acc[mi][ni]  = __builtin_amdgcn_mfma_f32_16x16x32_f16(ah[mi], bh[ni], acc[mi][ni], 0, 0, 0);
                acc2[mi][ni] = __builtin_amdgcn_mfma_f32_16x16x32_f16(ah[mi], bl[ni], acc2[mi][ni], 0, 0, 0);
                acc2[mi][ni] = __builtin_amdgcn_mfma_f32_16x16x32_f16(al[mi], bh[ni], acc2[mi][ni], 0, 0, 0);
            }
    }
    // epilogue: C layout col=lane&15, row=quad*4+reg; write split proj
    #pragma unroll
    for (int mi = 0; mi < 4; ++mi)
        #pragma unroll
        for (int r = 0; r < 4; ++r) {
            int row = mb * 128 + wm * 64 + mi * 16 + quad * 4 + r;
            #pragma unroll
            for (int ni = 0; ni < 4; ++ni) {
                int col = nb * 128 + wn * 64 + ni * 16 + l15;
                float v = acc[mi][ni][r] + acc2[mi][ni][r] * INV2048;
                Split s = split_f32(v);
                Ph[(size_t)row * 512 + col] = s.h;
                Pl[(size_t)row * 512 + col] = s.l;
            }
        }
}

// sim tile + fused partial argmax: A=proj [m][k], B=cn [c][k], K=512
__global__ __launch_bounds__(256, 2) void k_sim(const _Float16* __restrict__ Ah,
                                                const _Float16* __restrict__ Al,
                                                const _Float16* __restrict__ Bh,
                                                const _Float16* __restrict__ Bl,
                                                float* __restrict__ pval,
                                                int* __restrict__ pidx) {
    __shared__ _Float16 sAh[128 * 32], sAl[128 * 32], sBh[128 * 32], sBl[128 * 32];
    __shared__ float pv2[128][2];
    __shared__ int   pi2[128][2];
    const int t = threadIdx.x;
    const int cbk = blockIdx.x;  // 0..31 c-tiles
    const int mb = blockIdx.y;   // 0..255 m-tiles
    const int lane = t & 63, w = t >> 6;
    const int quad = lane >> 4, l15 = lane & 15;
    const int wm = w >> 1, wn = w & 1;

    f32x4 acc[4][4], acc2[4][4];
    const f32x4 z = {0.f, 0.f, 0.f, 0.f};
    #pragma unroll
    for (int i = 0; i < 4; ++i)
        #pragma unroll
        for (int j = 0; j < 4; ++j) { acc[i][j] = z; acc2[i][j] = z; }

    const int srow = w * 32 + (lane >> 2);
    const int kcol = (lane & 3) * 8;
    const _Float16* gAh = Ah + (size_t)(mb * 128 + srow) * 512 + kcol;
    const _Float16* gAl = Al + (size_t)(mb * 128 + srow) * 512 + kcol;
    const _Float16* gBh = Bh + (size_t)(cbk * 128 + srow) * 512 + kcol;
    const _Float16* gBl = Bl + (size_t)(cbk * 128 + srow) * 512 + kcol;

    for (int ks = 0; ks < 16; ++ks) {
        const int ko = ks * 32;
        __syncthreads();
        gl_lds16(gAh + ko, &sAh[w * 1024]);
        gl_lds16(gAh + ko + (size_t)16 * 512, &sAh[w * 1024 + 512]);
        gl_lds16(gAl + ko, &sAl[w * 1024]);
        gl_lds16(gAl + ko + (size_t)16 * 512, &sAl[w * 1024 + 512]);
        gl_lds16(gBh + ko, &sBh[w * 1024]);
        gl_lds16(gBh + ko + (size_t)16 * 512, &sBh[w * 1024 + 512]);
        gl_lds16(gBl + ko, &sBl[w * 1024]);
        gl_lds16(gBl + ko + (size_t)16 * 512, &sBl[w * 1024 + 512]);
        __syncthreads();
        half8 ah[4], al[4], bh[4], bl[4];
        #pragma unroll
        for (int i = 0; i < 4; ++i) {
            ah[i] = *(const half8*)&sAh[(wm * 64 + i * 16 + l15) * 32 + quad * 8];
            al[i] = *(const half8*)&sAl[(wm * 64 + i * 16 + l15) * 32 + quad * 8];
            bh[i] = *(const half8*)&sBh[(wn * 64 + i * 16 + l15) * 32 + quad * 8];
            bl[i] = *(const half8*)&sBl[(wn * 64 + i * 16 + l15) * 32 + quad * 8];
        }
        #pragma unroll
        for (int mi = 0; mi < 4; ++mi)
            #pragma unroll
            for (int ni = 0; ni < 4; ++ni) {
                acc[mi][ni]  = __builtin_amdgcn_mfma_f32_16x16x32_f16(ah[mi], bh[ni], acc[mi][ni], 0, 0, 0);
                acc2[mi][ni] = __builtin_amdgcn_mfma_f32_16x16x32_f16(ah[mi], bl[ni], acc2[mi][ni], 0, 0, 0);
                acc2[mi][ni] = __builtin_amdgcn_mfma_f32_16x16x32_f16(al[mi], bh[ni], acc2[mi][ni], 0, 0, 0);
            }
    }

    // fused partial argmax. row = wm*64+mi*16+quad*4+r ; col = wn*64+ni*16+l15
    #pragma unroll
    for (int mi = 0; mi < 4; ++mi)
        #pragma unroll
        for (int r = 0; r < 4; ++r) {
            float bv = -INFINITY;
            int bi = 0x7fffffff;
            #pragma unroll
            for (int ni = 0; ni < 4; ++ni) {
                float v = acc[mi][ni][r] + acc2[mi][ni][r] * INV2048;
                int col = cbk * 128 + wn * 64 + ni * 16 + l15;
                if (v > bv || (v == bv && col < bi)) { bv = v; bi = col; }
            }
            // reduce across the 16 lanes of this quad (same row, different cols)
            #pragma unroll
            for (int o = 1; o < 16; o <<= 1) {
                float ov = __shfl_xor(bv, o, 64);
                int oi = __shfl_xor(bi, o, 64);
                if (ov > bv || (ov == bv && oi < bi)) { bv = ov; bi = oi; }
            }
            if (l15 == 0) {
                int row = wm * 64 + mi * 16 + quad * 4 + r;
                pv2[row][wn] = bv;
                pi2[row][wn] = bi;
            }
        }
    __syncthreads();
    if (t < 128) {
        float v0 = pv2[t][0], v1 = pv2[t][1];
        int i0 = pi2[t][0], i1 = pi2[t][1];
        bool sw = (v1 > v0) || (v1 == v0 && i1 < i0);
        int m = mb * 128 + t;
        pval[(size_t)m * 32 + cbk] = sw ? v1 : v0;
        pidx[(size_t)m * 32 + cbk] = sw ? i1 : i0;
    }
}

__global__ __launch_bounds__(256) void k_final(const float* __restrict__ pval,
                                               const int* __restrict__ pidx,
                                               int* __restrict__ out) {
    int r = blockIdx.x * 256 + threadIdx.x;
    if (r >= 32768) return;
    float bv = -INFINITY;
    int bi = 0x7fffffff;
    #pragma unroll
    for (int j = 0; j < 32; ++j) {
        float v = pval[(size_t)r * 32 + j];
        int ci = pidx[(size_t)r * 32 + j];
        if (v > bv || (v == bv && ci < bi)) { bv = v; bi = ci; }
    }
    out[r] = bi;
}

extern "C" void kernel_launch(void* const* d_in, const int* in_sizes, int n_in,
                              void* d_out, int out_size, void* d_ws, size_t ws_size,
                              hipStream_t stream) {
    const float* x  = (const float*)d_in[0];   // [8,4096,1024]
    const float* rp = (const float*)d_in[1];   // [1024,512]
    const float* cb = (const float*)d_in[2];   // [4096,512]
    int* out = (int*)d_out;                    // [32768] int32

    char* ws = (char*)d_ws;
    _Float16* cn_h   = (_Float16*)(ws);
    _Float16* cn_l   = (_Float16*)(ws + ((size_t)4 << 20));
    _Float16* rpT_h  = (_Float16*)(ws + ((size_t)8 << 20));
    _Float16* rpT_l  = (_Float16*)(ws + ((size_t)9 << 20));
    _Float16* proj_h = (_Float16*)(ws + ((size_t)10 << 20));
    _Float16* proj_l = (_Float16*)(ws + ((size_t)42 << 20));
    float*    pval   = (float*)   (ws + ((size_t)74 << 20));
    int*      pidx   = (int*)     (ws + ((size_t)78 << 20));

    k_prep_rpt<<<dim3(16, 8), 256, 0, stream>>>(rp, rpT_h, rpT_l);
    k_norm_cb<<<4096, 256, 0, stream>>>(cb, cn_h, cn_l);
    k_gemm1<<<dim3(4, 256), 256, 0, stream>>>(x, rpT_h, rpT_l, proj_h, proj_l);
    k_sim<<<dim3(32, 256), 256, 0, stream>>>(proj_h, proj_l, cn_h, cn_l, pval, pidx);
    k_final<<<128, 256, 0, stream>>>(pval, pidx, out);
}

// Round 4
// 598.963 us; speedup vs baseline: 5.3109x; 1.3126x over previous
//
#include <hip/hip_runtime.h>
#include <math.h>

// B=8, N=4096, D=1024, E=512, C=4096.  M = 32768.
// Split-fp16 MFMA emulation of fp32 GEMM (a = h + l/2048, 3 MFMAs) for proj;
// hi-only fp16 pass for sim + deterministic margin rescue:
//   worst-case |sim_h - sim| <= 2^-10*||p||*||c|| + eps  < 0.03 = MARGIN
//   rows with top1-top2 < MARGIN recomputed with the exact 3-MFMA path.
//
// ws (MB): cn_h 0-4, cn_l 4-8, rpT_h 8-9, rpT_l 9-10, proj_h 10-42,
//          proj_l 42-74, pv1 74-78, pi1 78-82, pv2 82-86, rpv 86-90,
//          rpi 90-94, list 94-94.125, cnt @94.125

typedef _Float16 half8 __attribute__((ext_vector_type(8)));
typedef _Float16 half4 __attribute__((ext_vector_type(4)));
typedef float f32x4 __attribute__((ext_vector_type(4)));

#define INV2048 (4.8828125e-4f)
#define MARGIN 0.03f

struct Split { _Float16 h, l; };

__device__ __forceinline__ Split split_f32(float v) {
    Split s;
    s.h = (_Float16)v;
    s.l = (_Float16)((v - (float)s.h) * 2048.0f);
    return s;
}

__device__ __forceinline__ void gl_lds16(const void* g, void* l) {
    __builtin_amdgcn_global_load_lds(
        (const __attribute__((address_space(1))) unsigned int*)g,
        (__attribute__((address_space(3))) unsigned int*)l, 16, 0, 0);
}

// rp [1024,512] fp32 -> rpT_hi/lo [512,1024] f16; also zero-inits cnt
__global__ __launch_bounds__(256) void k_prep_rpt(const float* __restrict__ rp,
                                                  _Float16* __restrict__ th,
                                                  _Float16* __restrict__ tl,
                                                  int* __restrict__ cnt) {
    if (blockIdx.x == 0 && blockIdx.y == 0 && threadIdx.x == 0) *cnt = 0;
    __shared__ float tile[64][65];
    const int k0 = blockIdx.x * 64, n0 = blockIdx.y * 64;
    const int t = threadIdx.x;
    const int rr = t >> 6, cc = t & 63;
    #pragma unroll
    for (int i = 0; i < 16; ++i) {
        int r = i * 4 + rr;
        tile[r][cc] = rp[(size_t)(k0 + r) * 512 + n0 + cc];
    }
    __syncthreads();
    #pragma unroll
    for (int i = 0; i < 16; ++i) {
        int n = i * 4 + rr;
        Split s = split_f32(tile[cc][n]);
        size_t o = (size_t)(n0 + n) * 1024 + k0 + cc;
        th[o] = s.h;
        tl[o] = s.l;
    }
}

// codebook [4096,512] fp32 -> cn_hi/lo [4096,512] f16 (normalize + split)
__global__ __launch_bounds__(256) void k_norm_cb(const float* __restrict__ cb,
                                                 _Float16* __restrict__ ch,
                                                 _Float16* __restrict__ cl) {
    const int c = blockIdx.x;
    const int t = threadIdx.x;
    const float* row = cb + (size_t)c * 512;
    float v0 = row[t];
    float v1 = row[t + 256];
    float ss = v0 * v0 + v1 * v1;
    #pragma unroll
    for (int o = 32; o > 0; o >>= 1) ss += __shfl_down(ss, o, 64);
    __shared__ float wsum[4];
    if ((t & 63) == 0) wsum[t >> 6] = ss;
    __syncthreads();
    float s = 1.0f / fmaxf(sqrtf(wsum[0] + wsum[1] + wsum[2] + wsum[3]), 1e-12f);
    Split s0 = split_f32(v0 * s);
    ch[(size_t)c * 512 + t] = s0.h;
    cl[(size_t)c * 512 + t] = s0.l;
    Split s1 = split_f32(v1 * s);
    ch[(size_t)c * 512 + t + 256] = s1.h;
    cl[(size_t)c * 512 + t + 256] = s1.l;
}

// proj = x @ rp : M=32768, N=512, K=1024. split-fp16 3-MFMA (accurate).
__global__ __launch_bounds__(256, 2) void k_gemm1(const float* __restrict__ X,
                                                  const _Float16* __restrict__ Bh,
                                                  const _Float16* __restrict__ Bl,
                                                  _Float16* __restrict__ Ph,
                                                  _Float16* __restrict__ Pl) {
    __shared__ _Float16 sAh[128 * 32], sAl[128 * 32], sBh[128 * 32], sBl[128 * 32];
    const int t = threadIdx.x;
    const int nb = blockIdx.x;   // 0..3
    const int mb = blockIdx.y;   // 0..255
    const int lane = t & 63, w = t >> 6;
    const int quad = lane >> 4, l15 = lane & 15;
    const int wm = w >> 1, wn = w & 1;

    f32x4 acc[4][4], acc2[4][4];
    const f32x4 z = {0.f, 0.f, 0.f, 0.f};
    #pragma unroll
    for (int i = 0; i < 4; ++i)
        #pragma unroll
        for (int j = 0; j < 4; ++j) { acc[i][j] = z; acc2[i][j] = z; }

    const int srow = w * 32 + (lane >> 2);
    const int kcol = (lane & 3) * 8;
    const _Float16* gBh = Bh + (size_t)(nb * 128 + srow) * 1024 + kcol;
    const _Float16* gBl = Bl + (size_t)(nb * 128 + srow) * 1024 + kcol;
    const float* Xb = X + (size_t)(mb * 128) * 1024;

    for (int ks = 0; ks < 32; ++ks) {
        const int ko = ks * 32;
        __syncthreads();
        gl_lds16(gBh + ko, &sBh[w * 1024]);
        gl_lds16(gBh + ko + (size_t)16 * 1024, &sBh[w * 1024 + 512]);
        gl_lds16(gBl + ko, &sBl[w * 1024]);
        gl_lds16(gBl + ko + (size_t)16 * 1024, &sBl[w * 1024 + 512]);
        #pragma unroll
        for (int i = 0; i < 4; ++i) {
            int c = i * 256 + t;
            int row = c >> 3, kq = (c & 7) * 4;
            float4 v = *(const float4*)(Xb + (size_t)row * 1024 + ko + kq);
            Split sx = split_f32(v.x), sy = split_f32(v.y);
            Split sz = split_f32(v.z), sw = split_f32(v.w);
            half4 hv, lv;
            hv.x = sx.h; hv.y = sy.h; hv.z = sz.h; hv.w = sw.h;
            lv.x = sx.l; lv.y = sy.l; lv.z = sz.l; lv.w = sw.l;
            *(half4*)&sAh[row * 32 + kq] = hv;
            *(half4*)&sAl[row * 32 + kq] = lv;
        }
        __syncthreads();
        half8 ah[4], al[4], bh[4], bl[4];
        #pragma unroll
        for (int i = 0; i < 4; ++i) {
            ah[i] = *(const half8*)&sAh[(wm * 64 + i * 16 + l15) * 32 + quad * 8];
            al[i] = *(const half8*)&sAl[(wm * 64 + i * 16 + l15) * 32 + quad * 8];
            bh[i] = *(const half8*)&sBh[(wn * 64 + i * 16 + l15) * 32 + quad * 8];
            bl[i] = *(const half8*)&sBl[(wn * 64 + i * 16 + l15) * 32 + quad * 8];
        }
        #pragma unroll
        for (int mi = 0; mi < 4; ++mi)
            #pragma unroll
            for (int ni = 0; ni < 4; ++ni) {
                acc[mi][ni]  = __builtin_amdgcn_mfma_f32_16x16x32_f16(ah[mi], bh[ni], acc[mi][ni], 0, 0, 0);
                acc2[mi][ni] = __builtin_amdgcn_mfma_f32_16x16x32_f16(ah[mi], bl[ni], acc2[mi][ni], 0, 0, 0);
                acc2[mi][ni] = __builtin_amdgcn_mfma_f32_16x16x32_f16(al[mi], bh[ni], acc2[mi][ni], 0, 0, 0);
            }
    }
    #pragma unroll
    for (int mi = 0; mi < 4; ++mi)
        #pragma unroll
        for (int r = 0; r < 4; ++r) {
            int row = mb * 128 + wm * 64 + mi * 16 + quad * 4 + r;
            #pragma unroll
            for (int ni = 0; ni < 4; ++ni) {
                int col = nb * 128 + wn * 64 + ni * 16 + l15;
                float v = acc[mi][ni][r] + acc2[mi][ni][r] * INV2048;
                Split s = split_f32(v);
                Ph[(size_t)row * 512 + col] = s.h;
                Pl[(size_t)row * 512 + col] = s.l;
            }
        }
}

// PASS 1: hi-only sim + per-(row, c-tile) top-2 partials
__global__ __launch_bounds__(256, 4) void k_sim_h(const _Float16* __restrict__ Ah,
                                                  const _Float16* __restrict__ Bh,
                                                  float* __restrict__ pv1,
                                                  int* __restrict__ pi1,
                                                  float* __restrict__ pv2) {
    __shared__ _Float16 sAh[128 * 32], sBh[128 * 32];
    __shared__ float v1s[128][2], v2s[128][2];
    __shared__ int   i1s[128][2];
    const int t = threadIdx.x;
    const int cbk = blockIdx.x;  // 0..31
    const int mb = blockIdx.y;   // 0..255
    const int lane = t & 63, w = t >> 6;
    const int quad = lane >> 4, l15 = lane & 15;
    const int wm = w >> 1, wn = w & 1;

    f32x4 acc[4][4];
    const f32x4 z = {0.f, 0.f, 0.f, 0.f};
    #pragma unroll
    for (int i = 0; i < 4; ++i)
        #pragma unroll
        for (int j = 0; j < 4; ++j) acc[i][j] = z;

    const int srow = w * 32 + (lane >> 2);
    const int kcol = (lane & 3) * 8;
    const _Float16* gAh = Ah + (size_t)(mb * 128 + srow) * 512 + kcol;
    const _Float16* gBh = Bh + (size_t)(cbk * 128 + srow) * 512 + kcol;

    for (int ks = 0; ks < 16; ++ks) {
        const int ko = ks * 32;
        __syncthreads();
        gl_lds16(gAh + ko, &sAh[w * 1024]);
        gl_lds16(gAh + ko + (size_t)16 * 512, &sAh[w * 1024 + 512]);
        gl_lds16(gBh + ko, &sBh[w * 1024]);
        gl_lds16(gBh + ko + (size_t)16 * 512, &sBh[w * 1024 + 512]);
        __syncthreads();
        half8 ah[4], bh[4];
        #pragma unroll
        for (int i = 0; i < 4; ++i) {
            ah[i] = *(const half8*)&sAh[(wm * 64 + i * 16 + l15) * 32 + quad * 8];
            bh[i] = *(const half8*)&sBh[(wn * 64 + i * 16 + l15) * 32 + quad * 8];
        }
        #pragma unroll
        for (int mi = 0; mi < 4; ++mi)
            #pragma unroll
            for (int ni = 0; ni < 4; ++ni)
                acc[mi][ni] = __builtin_amdgcn_mfma_f32_16x16x32_f16(ah[mi], bh[ni], acc[mi][ni], 0, 0, 0);
    }

    // top-2 per row: lane-local over 4 cols, then 16-lane butterfly merge
    #pragma unroll
    for (int mi = 0; mi < 4; ++mi)
        #pragma unroll
        for (int r = 0; r < 4; ++r) {
            float v1 = -INFINITY, v2 = -INFINITY;
            int i1 = 0x7fffffff;
            #pragma unroll
            for (int ni = 0; ni < 4; ++ni) {
                float v = acc[mi][ni][r];
                int col = cbk * 128 + wn * 64 + ni * 16 + l15;
                if (v > v1 || (v == v1 && col < i1)) { v2 = v1; v1 = v; i1 = col; }
                else if (v > v2) v2 = v;
            }
            #pragma unroll
            for (int o = 1; o < 16; o <<= 1) {
                float ov1 = __shfl_xor(v1, o, 64);
                int oi1 = __shfl_xor(i1, o, 64);
                float ov2 = __shfl_xor(v2, o, 64);
                if (ov1 > v1 || (ov1 == v1 && oi1 < i1)) { v2 = fmaxf(v1, ov2); v1 = ov1; i1 = oi1; }
                else v2 = fmaxf(v2, ov1);
            }
            if (l15 == 0) {
                int row = wm * 64 + mi * 16 + quad * 4 + r;
                v1s[row][wn] = v1; i1s[row][wn] = i1; v2s[row][wn] = v2;
            }
        }
    __syncthreads();
    if (t < 128) {
        float v1 = v1s[t][0], v2 = v2s[t][0];
        int i1 = i1s[t][0];
        float ov1 = v1s[t][1], ov2 = v2s[t][1];
        int oi1 = i1s[t][1];
        if (ov1 > v1 || (ov1 == v1 && oi1 < i1)) { v2 = fmaxf(v1, ov2); v1 = ov1; i1 = oi1; }
        else v2 = fmaxf(v2, ov1);
        size_t o = (size_t)(mb * 128 + t) * 32 + cbk;
        pv1[o] = v1; pi1[o] = i1; pv2[o] = v2;
    }
}

// reduce 32 c-tile partials; commit confident rows, queue contested ones
__global__ __launch_bounds__(256) void k_flag(const float* __restrict__ pv1,
                                              const int* __restrict__ pi1,
                                              const float* __restrict__ pv2,
                                              int* __restrict__ out,
                                              int* __restrict__ list,
                                              int* __restrict__ cnt) {
    int r = blockIdx.x * 256 + threadIdx.x;
    if (r >= 32768) return;
    size_t base = (size_t)r * 32;
    float v1 = pv1[base], v2 = pv2[base];
    int i1 = pi1[base];
    #pragma unroll
    for (int j = 1; j < 32; ++j) {
        float ov1 = pv1[base + j], ov2 = pv2[base + j];
        int oi1 = pi1[base + j];
        if (ov1 > v1 || (ov1 == v1 && oi1 < i1)) { v2 = fmaxf(v1, ov2); v1 = ov1; i1 = oi1; }
        else v2 = fmaxf(v2, ov1);
    }
    out[r] = i1;
    if (v1 - v2 < MARGIN) {
        int p = atomicAdd(cnt, 1);
        list[p] = r;
    }
}

// PASS 2: exact 3-MFMA sim on gathered contested rows
__global__ __launch_bounds__(256, 2) void k_sim_fix(const _Float16* __restrict__ Ah,
                                                    const _Float16* __restrict__ Al,
                                                    const _Float16* __restrict__ Bh,
                                                    const _Float16* __restrict__ Bl,
                                                    const int* __restrict__ list,
                                                    const int* __restrict__ cnt,
                                                    float* __restrict__ rpv,
                                                    int* __restrict__ rpi) {
    __shared__ _Float16 sAh[128 * 32], sAl[128 * 32], sBh[128 * 32], sBl[128 * 32];
    __shared__ int rowidx[128];
    __shared__ float pvs[128][2];
    __shared__ int   pis[128][2];
    const int count = *cnt;
    const int t = threadIdx.x;
    const int cbk = blockIdx.x;  // 0..31
    const int lane = t & 63, w = t >> 6;
    const int quad = lane >> 4, l15 = lane & 15;
    const int wm = w >> 1, wn = w & 1;

    const int srow = w * 32 + (lane >> 2);
    const int kcol = (lane & 3) * 8;
    const _Float16* gBh = Bh + (size_t)(cbk * 128 + srow) * 512 + kcol;
    const _Float16* gBl = Bl + (size_t)(cbk * 128 + srow) * 512 + kcol;

    for (int g = blockIdx.y; g * 128 < count; g += gridDim.y) {
        __syncthreads();
        if (t < 128) {
            int p = g * 128 + t;
            rowidx[t] = (p < count) ? list[p] : list[0];
        }
        __syncthreads();

        f32x4 acc[4][4], acc2[4][4];
        const f32x4 z = {0.f, 0.f, 0.f, 0.f};
        #pragma unroll
        for (int i = 0; i < 4; ++i)
            #pragma unroll
            for (int j = 0; j < 4; ++j) { acc[i][j] = z; acc2[i][j] = z; }

        for (int ks = 0; ks < 16; ++ks) {
            const int ko = ks * 32;
            __syncthreads();
            gl_lds16(gBh + ko, &sBh[w * 1024]);
            gl_lds16(gBh + ko + (size_t)16 * 512, &sBh[w * 1024 + 512]);
            gl_lds16(gBl + ko, &sBl[w * 1024]);
            gl_lds16(gBl + ko + (size_t)16 * 512, &sBl[w * 1024 + 512]);
            #pragma unroll
            for (int i = 0; i < 2; ++i) {
                int idx = i * 256 + t;          // 0..511
                int row = idx >> 2, seg = (idx & 3) * 8;
                size_t src = (size_t)rowidx[row] * 512 + ko + seg;
                *(half8*)&sAh[row * 32 + seg] = *(const half8*)(Ah + src);
                *(half8*)&sAl[row * 32 + seg] = *(const half8*)(Al + src);
            }
            __syncthreads();
            half8 ah[4], al[4], bh[4], bl[4];
            #pragma unroll
            for (int i = 0; i < 4; ++i) {
                ah[i] = *(const half8*)&sAh[(wm * 64 + i * 16 + l15) * 32 + quad * 8];
                al[i] = *(const half8*)&sAl[(wm * 64 + i * 16 + l15) * 32 + quad * 8];
                bh[i] = *(const half8*)&sBh[(wn * 64 + i * 16 + l15) * 32 + quad * 8];
                bl[i] = *(const half8*)&sBl[(wn * 64 + i * 16 + l15) * 32 + quad * 8];
            }
            #pragma unroll
            for (int mi = 0; mi < 4; ++mi)
                #pragma unroll
                for (int ni = 0; ni < 4; ++ni) {
                    acc[mi][ni]  = __builtin_amdgcn_mfma_f32_16x16x32_f16(ah[mi], bh[ni], acc[mi][ni], 0, 0, 0);
                    acc2[mi][ni] = __builtin_amdgcn_mfma_f32_16x16x32_f16(ah[mi], bl[ni], acc2[mi][ni], 0, 0, 0);
                    acc2[mi][ni] = __builtin_amdgcn_mfma_f32_16x16x32_f16(al[mi], bh[ni], acc2[mi][ni], 0, 0, 0);
                }
        }

        #pragma unroll
        for (int mi = 0; mi < 4; ++mi)
            #pragma unroll
            for (int r = 0; r < 4; ++r) {
                float bv = -INFINITY;
                int bi = 0x7fffffff;
                #pragma unroll
                for (int ni = 0; ni < 4; ++ni) {
                    float v = acc[mi][ni][r] + acc2[mi][ni][r] * INV2048;
                    int col = cbk * 128 + wn * 64 + ni * 16 + l15;
                    if (v > bv || (v == bv && col < bi)) { bv = v; bi = col; }
                }
                #pragma unroll
                for (int o = 1; o < 16; o <<= 1) {
                    float ov = __shfl_xor(bv, o, 64);
                    int oi = __shfl_xor(bi, o, 64);
                    if (ov > bv || (ov == bv && oi < bi)) { bv = ov; bi = oi; }
                }
                if (l15 == 0) {
                    int row = wm * 64 + mi * 16 + quad * 4 + r;
                    pvs[row][wn] = bv; pis[row][wn] = bi;
                }
            }
        __syncthreads();
        if (t < 128 && g * 128 + t < count) {
            float v0 = pvs[t][0], v1 = pvs[t][1];
            int i0 = pis[t][0], i1 = pis[t][1];
            bool sw = (v1 > v0) || (v1 == v0 && i1 < i0);
            size_t o = (size_t)(g * 128 + t) * 32 + cbk;
            rpv[o] = sw ? v1 : v0;
            rpi[o] = sw ? i1 : i0;
        }
    }
}

__global__ __launch_bounds__(256) void k_fix(const float* __restrict__ rpv,
                                             const int* __restrict__ rpi,
                                             const int* __restrict__ list,
                                             const int* __restrict__ cnt,
                                             int* __restrict__ out) {
    int p = blockIdx.x * 256 + threadIdx.x;
    if (p >= *cnt) return;
    size_t base = (size_t)p * 32;
    float bv = -INFINITY;
    int bi = 0x7fffffff;
    #pragma unroll
    for (int j = 0; j < 32; ++j) {
        float v = rpv[base + j];
        int ci = rpi[base + j];
        if (v > bv || (v == bv && ci < bi)) { bv = v; bi = ci; }
    }
    out[list[p]] = bi;
}

extern "C" void kernel_launch(void* const* d_in, const int* in_sizes, int n_in,
                              void* d_out, int out_size, void* d_ws, size_t ws_size,
                              hipStream_t stream) {
    const float* x  = (const float*)d_in[0];   // [8,4096,1024]
    const float* rp = (const float*)d_in[1];   // [1024,512]
    const float* cb = (const float*)d_in[2];   // [4096,512]
    int* out = (int*)d_out;                    // [32768] int32

    char* ws = (char*)d_ws;
    _Float16* cn_h   = (_Float16*)(ws);
    _Float16* cn_l   = (_Float16*)(ws + ((size_t)4 << 20));
    _Float16* rpT_h  = (_Float16*)(ws + ((size_t)8 << 20));
    _Float16* rpT_l  = (_Float16*)(ws + ((size_t)9 << 20));
    _Float16* proj_h = (_Float16*)(ws + ((size_t)10 << 20));
    _Float16* proj_l = (_Float16*)(ws + ((size_t)42 << 20));
    float*    pv1    = (float*)   (ws + ((size_t)74 << 20));
    int*      pi1    = (int*)     (ws + ((size_t)78 << 20));
    float*    pv2    = (float*)   (ws + ((size_t)82 << 20));
    float*    rpv    = (float*)   (ws + ((size_t)86 << 20));
    int*      rpi    = (int*)     (ws + ((size_t)90 << 20));
    int*      list   = (int*)     (ws + ((size_t)94 << 20));
    int*      cnt    = (int*)     (ws + ((size_t)94 << 20) + (128 << 10));

    k_prep_rpt<<<dim3(16, 8), 256, 0, stream>>>(rp, rpT_h, rpT_l, cnt);
    k_norm_cb<<<4096, 256, 0, stream>>>(cb, cn_h, cn_l);
    k_gemm1<<<dim3(4, 256), 256, 0, stream>>>(x, rpT_h, rpT_l, proj_h, proj_l);
    k_sim_h<<<dim3(32, 256), 256, 0, stream>>>(proj_h, cn_h, pv1, pi1, pv2);
    k_flag<<<128, 256, 0, stream>>>(pv1, pi1, pv2, out, list, cnt);
    k_sim_fix<<<dim3(32, 32), 256, 0, stream>>>(proj_h, proj_l, cn_h, cn_l, list, cnt, rpv, rpi);
    k_fix<<<128, 256, 0, stream>>>(rpv, rpi, list, cnt, out);
}